// Round 12
// baseline (523.239 us; speedup 1.0000x reference)
//
#include <hip/hip_runtime.h>

#define NF 8192
#define KN 48
#define TM 4

typedef __attribute__((ext_vector_type(8))) short short8;
typedef __attribute__((ext_vector_type(4))) float f32x4;

__device__ __forceinline__ unsigned short bf16e(float f) {
    return (unsigned short)((__float_as_uint(f) + 0x8000u) >> 16);
}

// ---------------------------------------------------------------------------
// geometry: ball->cube + trilinear corner weights for one neighbor
// packs 8 entries of (tap<<16 | bf16(weight)) into g[0..7]
// ---------------------------------------------------------------------------
__device__ __forceinline__ void pn_geom(float rx, float ry, float rz, unsigned* g)
{
    float d2  = rx * rx + ry * ry + rz * rz;
    float om  = 1.0f - d2;
    float win = om * om * om;
    win = fminf(fmaxf(win, 0.0f), 1.0f);

    float rxy2 = rx * rx + ry * ry;
    float rho  = sqrtf(rxy2 + rz * rz + 1e-8f);
    float rxyv = sqrtf(rxy2 + 1e-8f);
    bool  pole = (rxy2 <= 1.25f * rz * rz);
    float s    = pole ? sqrtf(3.0f * rho / (rho + fabsf(rz))) : (rho / rxyv);
    float cx = rx * s, cy = ry * s;
    float sgnz = (rz > 0.0f) ? 1.0f : ((rz < 0.0f) ? -1.0f : 0.0f);
    float cz   = pole ? sgnz * rho : 1.5f * rz;

    float rr   = sqrtf(cx * cx + cy * cy + 1e-8f);
    bool  cond = fabsf(cx) >= fabsf(cy);
    float sx = (cx >= 0.0f) ? 1.0f : -1.0f;
    float sy = (cy >= 0.0f) ? 1.0f : -1.0f;
    float safecx = (fabsf(cx) > 1e-8f) ? cx : 1.0f;
    float safecy = (fabsf(cy) > 1e-8f) ? cy : 1.0f;
    const float C4PI = 1.2732395447351628f;
    float u = cond ? (sx * rr) : (sy * C4PI * rr * atanf(cx / safecy));
    float v = cond ? (sx * C4PI * rr * atanf(cy / safecx)) : (sy * rr);
    if (rho < 1e-6f) { u = 0.0f; v = 0.0f; cz = 0.0f; }

    float tx = fminf(fmaxf((u  * 0.5f + 0.5f) * 3.0f, 0.0f), 3.0f);
    float ty = fminf(fmaxf((v  * 0.5f + 0.5f) * 3.0f, 0.0f), 3.0f);
    float tz = fminf(fmaxf((cz * 0.5f + 0.5f) * 3.0f, 0.0f), 3.0f);
    int ix = (int)floorf(tx); ix = ix < 0 ? 0 : (ix > 2 ? 2 : ix);
    int iy = (int)floorf(ty); iy = iy < 0 ? 0 : (iy > 2 ? 2 : iy);
    int iz = (int)floorf(tz); iz = iz < 0 ? 0 : (iz > 2 ? 2 : iz);
    float fx = tx - (float)ix, fy = ty - (float)iy, fz = tz - (float)iz;
    float wx0 = 1.0f - fx, wy0 = 1.0f - fy, wz0 = 1.0f - fz;

#pragma unroll
    for (int dx = 0; dx < 2; ++dx)
#pragma unroll
        for (int dy = 0; dy < 2; ++dy)
#pragma unroll
            for (int dz = 0; dz < 2; ++dz) {
                float w = (dx ? fx : wx0) * (dy ? fy : wy0) * (dz ? fz : wz0) * win;
                int tap = ((ix + dx) << 4) + ((iy + dy) << 2) + (iz + dz);
                g[(dx << 2) | (dy << 1) | dz] = ((unsigned)tap << 16) | (unsigned)bf16e(w);
            }
}

// ---------------------------------------------------------------------------
// prep: vel_new/pos_new, fluid feats, neighbor count, dense d0 branch
// ---------------------------------------------------------------------------
__global__ void __launch_bounds__(256) pn_prep(
    const float* __restrict__ pos, const float* __restrict__ vel,
    const int* __restrict__ nbrf,
    const float* __restrict__ d0w, const float* __restrict__ d0b,
    float* __restrict__ pos_new, float* __restrict__ feats0,
    float* __restrict__ X, float* __restrict__ nfn)
{
    int t = blockIdx.x * 256 + threadIdx.x;
    if (t >= NF) return;
    float vx = vel[t * 3 + 0], vy = vel[t * 3 + 1], vz = vel[t * 3 + 2];
    float vnx = vx, vny = vy - 9.81f * 0.02f, vnz = vz;
    float pnx = pos[t * 3 + 0] + (vx + vnx) * 0.01f;
    float pny = pos[t * 3 + 1] + (vy + vny) * 0.01f;
    float pnz = pos[t * 3 + 2] + (vz + vnz) * 0.01f;
    pos_new[t * 3 + 0] = pnx; pos_new[t * 3 + 1] = pny; pos_new[t * 3 + 2] = pnz;
    feats0[t * 4 + 0] = 1.0f; feats0[t * 4 + 1] = vnx;
    feats0[t * 4 + 2] = vny;  feats0[t * 4 + 3] = vnz;
    int cnt = 0;
    for (int k = 0; k < KN; ++k) cnt += (nbrf[t * KN + k] >= 0) ? 1 : 0;
    nfn[t] = (float)cnt;
    for (int j = 0; j < 32; ++j) {
        float s = d0b[j] + d0w[0 * 32 + j] + vnx * d0w[1 * 32 + j]
                + vny * d0w[2 * 32 + j] + vnz * d0w[3 * 32 + j];
        X[t * 96 + 64 + j] = s;
    }
}

// ---------------------------------------------------------------------------
// pack:  F2t[cc][dt][dd 16][k2 = tap*16+cl : 1024]  (B^T, K contiguous, bf16)
//        FD[d][CINP] (dense branch, B^T), B = cb (+db)
// ---------------------------------------------------------------------------
template <int CIN, int COUT, int HAS_SELF>
__global__ void __launch_bounds__(256) pn_pack(
    const float* __restrict__ cw, const float* __restrict__ dw,
    const float* __restrict__ cb, const float* __restrict__ db,
    unsigned short* __restrict__ F2t, unsigned short* __restrict__ FD,
    float* __restrict__ B)
{
    constexpr int CINP = ((CIN + 15) / 16) * 16;
    constexpr int NCC  = CINP / 16;
    constexpr int DPAD = ((COUT + 15) / 16) * 16;
    constexpr int NT   = DPAD / 16;
    const int total1 = NCC * NT * 16 * 1024;
    const int total2 = HAS_SELF ? DPAD * CINP : 0;
    int i = blockIdx.x * 256 + threadIdx.x;
    if (i < total1) {
        int k2 = i & 1023;
        int q  = i >> 10;
        int dd = q & 15; q >>= 4;
        int dt = q % NT;
        int cc = q / NT;
        int t   = k2 >> 4;
        int cin = cc * 16 + (k2 & 15);
        int d   = dt * 16 + dd;
        float v = 0.0f;
        if (cin < CIN && d < COUT) v = cw[((size_t)t * CIN + cin) * COUT + d];
        F2t[i] = bf16e(v);
    } else if (i < total1 + total2) {
        int j = i - total1;
        int d = j / CINP, c = j % CINP;
        float v = 0.0f;
        if (c < CIN && d < COUT) v = dw[(size_t)c * COUT + d];
        FD[j] = bf16e(v);
    }
    if (i < COUT) B[i] = cb[i] + (HAS_SELF ? db[i] : 0.0f);
}

// ---------------------------------------------------------------------------
// fused CConv, all-MFMA, W64-persistent, TM=4 / 256 thr (~38KB LDS ->
// 4 independent blocks/CU for phase interleave):
//   geometry held in REGISTERS (thread owns one (pt,k) entry)
//   per cc: step1 MFMA (all 4 mt) -> bar -> [stage(cc+1) || step2 MFMA] -> bar
// NOTE: MFMA is wave-cooperative — never branch around it with a
//       lane-divergent condition; zero the fragments instead (round-8 bug).
// OUT_MODE: 0 = X-slice, 1 = plain, 2 = +resid, 3 = final pos/vel
// ---------------------------------------------------------------------------
template <int CIN, int COUT, int HAS_SELF, int RELU_IN, int OUT_MODE>
__global__ void __launch_bounds__(256, 4) pn_cconv(
    const float* __restrict__ qpos, const float* __restrict__ ppos,
    const float* __restrict__ feats, const int* __restrict__ nbr,
    const unsigned short* __restrict__ F2t, const unsigned short* __restrict__ FD,
    const float* __restrict__ bias,
    const float* __restrict__ resid, float* __restrict__ outp,
    const float* __restrict__ pos0, int out_stride, int out_off)
{
    constexpr int CINP   = ((CIN + 15) / 16) * 16;
    constexpr int NCC    = CINP / 16;
    constexpr int DPAD   = ((COUT + 15) / 16) * 16;
    constexpr int NT     = DPAD / 16;
    constexpr int NW     = 4;             // waves per block
    constexpr int SPLITK = NW / NT;
    constexpr int SPC2   = 32 / SPLITK;   // 32-wide K-steps per wave in step2
    constexpr int WST    = 48;            // row stride (bf16), 96B, 16B-aligned
    constexpr int A2ST   = 1032;          // A2 row stride (2064B, 16B-aligned)

    __shared__ __align__(16) unsigned short sW [TM * 64 * WST];   // 24576B
    __shared__ __align__(16) unsigned short sFT[TM * 16 * WST];   // 6144B (aliased late)
    __shared__ __align__(16) unsigned short sA2[TM * A2ST];       // 8256B

    float*          sEpi = (float*)sFT;            // 4096B, after sFT dead
    unsigned short* sA3  = sFT + 2304;             // byte 4608.., after sFT dead

    const int tid  = threadIdx.x;
    const int w    = tid >> 6;
    const int lane = tid & 63;
    const int n16  = lane & 15;
    const int kg   = lane >> 4;
    const int pt0  = blockIdx.x * TM;
    const int dt   = w % NT;
    const int kh   = w / NT;

    // phase 0: geometry into REGISTERS (thread owns entry (myPt, myK))
    const int myPt = tid / KN;
    const int myK  = tid - myPt * KN;
    int      myId  = -1;
    unsigned g[8];
    if (tid < TM * KN) {
        int q = pt0 + myPt;
        myId  = nbr[q * KN + myK];
        if (myId >= 0) {
            float rx = (ppos[myId * 3 + 0] - qpos[q * 3 + 0]) * (1.0f / 0.1125f);
            float ry = (ppos[myId * 3 + 1] - qpos[q * 3 + 1]) * (1.0f / 0.1125f);
            float rz = (ppos[myId * 3 + 2] - qpos[q * 3 + 2]) * (1.0f / 0.1125f);
            pn_geom(rx, ry, rz, g);
        }
    }

    // staging helper: thread writes its entry's 16-chan slice (zeros if invalid)
    auto stage = [&](int cc) {
        if (tid < TM * KN) {
            const int cb0 = cc * 16;
            unsigned short vals[16];
            if (myId >= 0) {
                if constexpr (CIN % 16 == 0) {
                    const float4* s4 = (const float4*)(feats + (size_t)myId * CIN + cb0);
#pragma unroll
                    for (int v4 = 0; v4 < 4; ++v4) {
                        float4 f = s4[v4];
                        if (RELU_IN) { f.x=fmaxf(f.x,0.f); f.y=fmaxf(f.y,0.f); f.z=fmaxf(f.z,0.f); f.w=fmaxf(f.w,0.f); }
                        vals[v4*4+0] = bf16e(f.x); vals[v4*4+1] = bf16e(f.y);
                        vals[v4*4+2] = bf16e(f.z); vals[v4*4+3] = bf16e(f.w);
                    }
                } else {
#pragma unroll
                    for (int c = 0; c < 16; ++c) {
                        float f = (cb0 + c < CIN) ? feats[(size_t)myId * CIN + cb0 + c] : 0.0f;
                        if (RELU_IN) f = fmaxf(f, 0.0f);
                        vals[c] = bf16e(f);
                    }
                }
            } else {
#pragma unroll
                for (int c = 0; c < 16; ++c) vals[c] = 0;
            }
#pragma unroll
            for (int c = 0; c < 16; ++c) sFT[(myPt * 16 + c) * WST + myK] = vals[c];
        }
    };

    // zero W64 once
    {
        uint4 z4 = make_uint4(0, 0, 0, 0);
        for (int i = tid; i < TM * 64 * WST / 8; i += 256) ((uint4*)sW)[i] = z4;
    }
    __syncthreads();
    // scatter W64 from register geometry (write-once, no atomics) + stage cc=0
    if (tid < TM * KN && myId >= 0) {
#pragma unroll
        for (int j = 0; j < 8; ++j)
            sW[(myPt * 64 + (int)(g[j] >> 16)) * WST + myK] = (unsigned short)(g[j] & 0xffffu);
    }
    stage(0);

    f32x4 accA = {0.0f, 0.0f, 0.0f, 0.0f};
    f32x4 accB = {0.0f, 0.0f, 0.0f, 0.0f};
    const short8 z8 = {0,0,0,0,0,0,0,0};
    __syncthreads();

    for (int cc = 0; cc < NCC; ++cc) {
        // step1 merged over mt: A2[pt][tap*16+c] for all 64 taps; wave w -> pt w
        {
            short8 bvv[2];
#pragma unroll
            for (int s = 0; s < 2; ++s) {
                int kidx = s * 32 + kg * 8;
                bvv[s] = z8;
                if (kidx < KN)
                    bvv[s] = *(const short8*)(sFT + (w * 16 + n16) * WST + kidx);
            }
#pragma unroll
            for (int mt = 0; mt < 4; ++mt) {
                f32x4 a1 = {0.0f, 0.0f, 0.0f, 0.0f};
#pragma unroll
                for (int s = 0; s < 2; ++s) {
                    int kidx = s * 32 + kg * 8;
                    short8 av = z8;
                    if (kidx < KN)
                        av = *(const short8*)(sW + (w * 64 + mt * 16 + n16) * WST + kidx);
                    a1 = __builtin_amdgcn_mfma_f32_16x16x32_bf16(av, bvv[s], a1, 0, 0, 0);
                }
#pragma unroll
                for (int r = 0; r < 4; ++r)
                    sA2[w * A2ST + (mt * 16 + kg * 4 + r) * 16 + n16] = bf16e(a1[r]);
            }
        }
        __syncthreads();

        // stage(cc+1) overlapped with step2 (independent LDS regions)
        if (cc + 1 < NCC) stage(cc + 1);

        // step2: acc += A2(TM pts x 1024) * F2t(1024 x DPAD); wave (dt,kh); dual acc
        {
            const unsigned short* gB = F2t + ((size_t)((cc * NT + dt) * 16 + n16)) * 1024;
            const int s0 = kh * SPC2;
#pragma unroll 4
            for (int s2 = 0; s2 < SPC2; ++s2) {
                int k2 = (s0 + s2) * 32 + kg * 8;
                short8 av = (n16 < TM) ? *(const short8*)(sA2 + n16 * A2ST + k2) : z8;
                short8 bv = *(const short8*)(gB + k2);
                if (s2 & 1) accB = __builtin_amdgcn_mfma_f32_16x16x32_bf16(av, bv, accB, 0, 0, 0);
                else        accA = __builtin_amdgcn_mfma_f32_16x16x32_bf16(av, bv, accA, 0, 0, 0);
            }
        }
        __syncthreads();
    }

    // self/dense branch: acc += relu(self feats) x FD   (sA3 aliases dead sFT)
    if constexpr (HAS_SELF) {
        constexpr int NP = NCC / 2;
        for (int ccp = 0; ccp < NP; ++ccp) {
            if (tid < TM * 32) {
                int pt = tid / 32, c = tid & 31;
                int cin = ccp * 32 + c;
                float f = (cin < CIN) ? feats[(size_t)(pt0 + pt) * CIN + cin] : 0.0f;
                if (RELU_IN) f = fmaxf(f, 0.0f);
                sA3[pt * 40 + c] = bf16e(f);
            }
            __syncthreads();
            if (ccp % SPLITK == kh) {    // wave-uniform condition: safe around MFMA
                short8 av = (n16 < TM) ? *(const short8*)(sA3 + n16 * 40 + kg * 8) : z8;
                short8 bv = *(const short8*)(FD + (size_t)(dt * 16 + n16) * CINP + ccp * 32 + kg * 8);
                accA = __builtin_amdgcn_mfma_f32_16x16x32_bf16(av, bv, accA, 0, 0, 0);
            }
            __syncthreads();
        }
    }

    // epilogue: split-K combine + bias + output modes (sEpi aliases dead sFT)
#pragma unroll
    for (int r = 0; r < 4; ++r) sEpi[(w * 64 + lane) * 4 + r] = accA[r] + accB[r];
    __syncthreads();

    if (w < NT) {
        float sum[4];
#pragma unroll
        for (int r = 0; r < 4; ++r) {
            float s = 0.0f;
#pragma unroll
            for (int k = 0; k < SPLITK; ++k)
                s += sEpi[((k * NT + w) * 64 + lane) * 4 + r];
            sum[r] = s;
        }
        int d = w * 16 + n16;
        if (d < COUT) {
            float b = bias[d];
#pragma unroll
            for (int r = 0; r < 4; ++r) {
                int pt = kg * 4 + r;
                if (pt < TM) {
                    int q = pt0 + pt;
                    float y = sum[r] + b;
                    if constexpr (OUT_MODE == 0) {
                        outp[q * out_stride + out_off + d] = y;
                    } else if constexpr (OUT_MODE == 1) {
                        outp[q * COUT + d] = y;
                    } else if constexpr (OUT_MODE == 2) {
                        outp[q * COUT + d] = y + resid[q * COUT + d];
                    } else {
                        float corr = y * (1.0f / 128.0f);
                        float pn   = qpos[q * 3 + d];
                        float pc   = pn + corr;
                        outp[q * 3 + d]          = pc;
                        outp[NF * 3 + q * 3 + d] = (pc - pos0[q * 3 + d]) * (1.0f / 0.02f);
                    }
                }
            }
        }
    }
}

// ---------------------------------------------------------------------------
// host launcher
// ---------------------------------------------------------------------------
extern "C" void kernel_launch(void* const* d_in, const int* in_sizes, int n_in,
                              void* d_out, int out_size, void* d_ws, size_t ws_size,
                              hipStream_t stream)
{
    (void)in_sizes; (void)n_in; (void)out_size; (void)ws_size;

    const float* pos       = (const float*)d_in[0];
    const float* vel       = (const float*)d_in[1];
    const float* box       = (const float*)d_in[2];
    const float* box_feats = (const float*)d_in[3];
    const int*   nbrf      = (const int*)d_in[4];
    const int*   nbrb      = (const int*)d_in[5];
    const float* cf0_w = (const float*)d_in[6];
    const float* cf0_b = (const float*)d_in[7];
    const float* co0_w = (const float*)d_in[8];
    const float* co0_b = (const float*)d_in[9];
    const float* d0_w  = (const float*)d_in[10];
    const float* d0_b  = (const float*)d_in[11];
    const float* c1_w  = (const float*)d_in[12];
    const float* c1_b  = (const float*)d_in[13];
    const float* d1_w  = (const float*)d_in[14];
    const float* d1_b  = (const float*)d_in[15];
    const float* c2_w  = (const float*)d_in[16];
    const float* c2_b  = (const float*)d_in[17];
    const float* d2_w  = (const float*)d_in[18];
    const float* d2_b  = (const float*)d_in[19];
    const float* c3_w  = (const float*)d_in[20];
    const float* c3_b  = (const float*)d_in[21];
    const float* d3_w  = (const float*)d_in[22];
    const float* d3_b  = (const float*)d_in[23];

    char* ws = (char*)d_ws;
    float*          POSNEW = (float*)(ws + 0);        // 98304
    float*          FEATS0 = (float*)(ws + 98304);    // 131072
    float*          X      = (float*)(ws + 229376);   // 8192*96*4 = 3145728
    float*          X1     = (float*)(ws + 3375104);  // 2097152
    float*          X2     = (float*)(ws + 5472256);  // 2097152
    unsigned short* F2T1   = (unsigned short*)(ws + 7569408); // 786432
    unsigned short* F2T2   = (unsigned short*)(ws + 8355840); // 524288
    unsigned short* F2T3   = (unsigned short*)(ws + 8880128); // 131072
    unsigned short* F2Tf   = (unsigned short*)(ws + 9011200); // 65536
    unsigned short* F2To   = (unsigned short*)(ws + 9076736); // 65536
    unsigned short* FD1    = (unsigned short*)(ws + 9142272); // 12288
    unsigned short* FD2    = (unsigned short*)(ws + 9154560); // 8192
    unsigned short* FD3    = (unsigned short*)(ws + 9162752); // 2048
    float*          B1     = (float*)(ws + 9164800);
    float*          B2     = (float*)(ws + 9165056);
    float*          B3     = (float*)(ws + 9165312);
    float*          Bf0    = (float*)(ws + 9165568);
    float*          Bo0    = (float*)(ws + 9165824);

    float* out_f = (float*)d_out;

    // packs: <CIN, COUT, HAS_SELF>; grid covers F2t + FD
    pn_pack<96, 64, 1><<<(6*4*16*1024 + 64*96 + 255) / 256, 256, 0, stream>>>(c1_w, d1_w, c1_b, d1_b, F2T1, FD1, B1);
    pn_pack<64, 64, 1><<<(4*4*16*1024 + 64*64 + 255) / 256, 256, 0, stream>>>(c2_w, d2_w, c2_b, d2_b, F2T2, FD2, B2);
    pn_pack<64, 3, 1><<<(4*1*16*1024 + 16*64 + 255) / 256, 256, 0, stream>>>(c3_w, d3_w, c3_b, d3_b, F2T3, FD3, B3);
    pn_pack<4, 32, 0><<<(1*2*16*1024 + 255) / 256, 256, 0, stream>>>(cf0_w, nullptr, cf0_b, nullptr, F2Tf, nullptr, Bf0);
    pn_pack<3, 32, 0><<<(1*2*16*1024 + 255) / 256, 256, 0, stream>>>(co0_w, nullptr, co0_b, nullptr, F2To, nullptr, Bo0);

    pn_prep<<<(NF + 255) / 256, 256, 0, stream>>>(pos, vel, nbrf, d0_w, d0_b,
                                                  POSNEW, FEATS0, X, out_f + NF * 6);

    // convs: <CIN, COUT, HAS_SELF, RELU_IN, OUT_MODE>, grid NF/4, 256 thr
    pn_cconv<4, 32, 0, 0, 0><<<NF / TM, 256, 0, stream>>>(
        POSNEW, POSNEW, FEATS0, nbrf, F2Tf, nullptr, Bf0, nullptr, X, nullptr, 96, 32);
    pn_cconv<3, 32, 0, 0, 0><<<NF / TM, 256, 0, stream>>>(
        POSNEW, box, box_feats, nbrb, F2To, nullptr, Bo0, nullptr, X, nullptr, 96, 0);
    pn_cconv<96, 64, 1, 1, 1><<<NF / TM, 256, 0, stream>>>(
        POSNEW, POSNEW, X, nbrf, F2T1, FD1, B1, nullptr, X1, nullptr, 0, 0);
    pn_cconv<64, 64, 1, 1, 2><<<NF / TM, 256, 0, stream>>>(
        POSNEW, POSNEW, X1, nbrf, F2T2, FD2, B2, X1, X2, nullptr, 0, 0);
    pn_cconv<64, 3, 1, 1, 3><<<NF / TM, 256, 0, stream>>>(
        POSNEW, POSNEW, X2, nbrf, F2T3, FD3, B3, nullptr, out_f, pos, 0, 0);
}

// Round 13
// 371.562 us; speedup vs baseline: 1.4082x; 1.4082x over previous
//
#include <hip/hip_runtime.h>

#define NF 8192
#define KN 48
#define TM 8

typedef __attribute__((ext_vector_type(8))) short short8;
typedef __attribute__((ext_vector_type(4))) float f32x4;

__device__ __forceinline__ unsigned short bf16e(float f) {
    return (unsigned short)((__float_as_uint(f) + 0x8000u) >> 16);
}

// ---------------------------------------------------------------------------
// geometry: ball->cube + trilinear corner weights for one neighbor
// packs 8 entries of (tap<<16 | bf16(weight)) into g[0..7]
// ---------------------------------------------------------------------------
__device__ __forceinline__ void pn_geom(float rx, float ry, float rz, unsigned* g)
{
    float d2  = rx * rx + ry * ry + rz * rz;
    float om  = 1.0f - d2;
    float win = om * om * om;
    win = fminf(fmaxf(win, 0.0f), 1.0f);

    float rxy2 = rx * rx + ry * ry;
    float rho  = sqrtf(rxy2 + rz * rz + 1e-8f);
    float rxyv = sqrtf(rxy2 + 1e-8f);
    bool  pole = (rxy2 <= 1.25f * rz * rz);
    float s    = pole ? sqrtf(3.0f * rho / (rho + fabsf(rz))) : (rho / rxyv);
    float cx = rx * s, cy = ry * s;
    float sgnz = (rz > 0.0f) ? 1.0f : ((rz < 0.0f) ? -1.0f : 0.0f);
    float cz   = pole ? sgnz * rho : 1.5f * rz;

    float rr   = sqrtf(cx * cx + cy * cy + 1e-8f);
    bool  cond = fabsf(cx) >= fabsf(cy);
    float sx = (cx >= 0.0f) ? 1.0f : -1.0f;
    float sy = (cy >= 0.0f) ? 1.0f : -1.0f;
    float safecx = (fabsf(cx) > 1e-8f) ? cx : 1.0f;
    float safecy = (fabsf(cy) > 1e-8f) ? cy : 1.0f;
    const float C4PI = 1.2732395447351628f;
    float u = cond ? (sx * rr) : (sy * C4PI * rr * atanf(cx / safecy));
    float v = cond ? (sx * C4PI * rr * atanf(cy / safecx)) : (sy * rr);
    if (rho < 1e-6f) { u = 0.0f; v = 0.0f; cz = 0.0f; }

    float tx = fminf(fmaxf((u  * 0.5f + 0.5f) * 3.0f, 0.0f), 3.0f);
    float ty = fminf(fmaxf((v  * 0.5f + 0.5f) * 3.0f, 0.0f), 3.0f);
    float tz = fminf(fmaxf((cz * 0.5f + 0.5f) * 3.0f, 0.0f), 3.0f);
    int ix = (int)floorf(tx); ix = ix < 0 ? 0 : (ix > 2 ? 2 : ix);
    int iy = (int)floorf(ty); iy = iy < 0 ? 0 : (iy > 2 ? 2 : iy);
    int iz = (int)floorf(tz); iz = iz < 0 ? 0 : (iz > 2 ? 2 : iz);
    float fx = tx - (float)ix, fy = ty - (float)iy, fz = tz - (float)iz;
    float wx0 = 1.0f - fx, wy0 = 1.0f - fy, wz0 = 1.0f - fz;

#pragma unroll
    for (int dx = 0; dx < 2; ++dx)
#pragma unroll
        for (int dy = 0; dy < 2; ++dy)
#pragma unroll
            for (int dz = 0; dz < 2; ++dz) {
                float w = (dx ? fx : wx0) * (dy ? fy : wy0) * (dz ? fz : wz0) * win;
                int tap = ((ix + dx) << 4) + ((iy + dy) << 2) + (iz + dz);
                g[(dx << 2) | (dy << 1) | dz] = ((unsigned)tap << 16) | (unsigned)bf16e(w);
            }
}

// ---------------------------------------------------------------------------
// prep: vel_new/pos_new, fluid feats, neighbor count, dense d0 branch
// ---------------------------------------------------------------------------
__global__ void __launch_bounds__(256) pn_prep(
    const float* __restrict__ pos, const float* __restrict__ vel,
    const int* __restrict__ nbrf,
    const float* __restrict__ d0w, const float* __restrict__ d0b,
    float* __restrict__ pos_new, float* __restrict__ feats0,
    float* __restrict__ X, float* __restrict__ nfn)
{
    int t = blockIdx.x * 256 + threadIdx.x;
    if (t >= NF) return;
    float vx = vel[t * 3 + 0], vy = vel[t * 3 + 1], vz = vel[t * 3 + 2];
    float vnx = vx, vny = vy - 9.81f * 0.02f, vnz = vz;
    float pnx = pos[t * 3 + 0] + (vx + vnx) * 0.01f;
    float pny = pos[t * 3 + 1] + (vy + vny) * 0.01f;
    float pnz = pos[t * 3 + 2] + (vz + vnz) * 0.01f;
    pos_new[t * 3 + 0] = pnx; pos_new[t * 3 + 1] = pny; pos_new[t * 3 + 2] = pnz;
    feats0[t * 4 + 0] = 1.0f; feats0[t * 4 + 1] = vnx;
    feats0[t * 4 + 2] = vny;  feats0[t * 4 + 3] = vnz;
    int cnt = 0;
    for (int k = 0; k < KN; ++k) cnt += (nbrf[t * KN + k] >= 0) ? 1 : 0;
    nfn[t] = (float)cnt;
    for (int j = 0; j < 32; ++j) {
        float s = d0b[j] + d0w[0 * 32 + j] + vnx * d0w[1 * 32 + j]
                + vny * d0w[2 * 32 + j] + vnz * d0w[3 * 32 + j];
        X[t * 96 + 64 + j] = s;
    }
}

// ---------------------------------------------------------------------------
// pack:  F2t[cc][dt][dd 16][k2 = tap*16+cl : 1024]  (B^T, K contiguous, bf16)
//        FD[d][CINP] (dense branch, B^T), B = cb (+db)
// ---------------------------------------------------------------------------
template <int CIN, int COUT, int HAS_SELF>
__global__ void __launch_bounds__(256) pn_pack(
    const float* __restrict__ cw, const float* __restrict__ dw,
    const float* __restrict__ cb, const float* __restrict__ db,
    unsigned short* __restrict__ F2t, unsigned short* __restrict__ FD,
    float* __restrict__ B)
{
    constexpr int CINP = ((CIN + 15) / 16) * 16;
    constexpr int NCC  = CINP / 16;
    constexpr int DPAD = ((COUT + 15) / 16) * 16;
    constexpr int NT   = DPAD / 16;
    const int total1 = NCC * NT * 16 * 1024;
    const int total2 = HAS_SELF ? DPAD * CINP : 0;
    int i = blockIdx.x * 256 + threadIdx.x;
    if (i < total1) {
        int k2 = i & 1023;
        int q  = i >> 10;
        int dd = q & 15; q >>= 4;
        int dt = q % NT;
        int cc = q / NT;
        int t   = k2 >> 4;
        int cin = cc * 16 + (k2 & 15);
        int d   = dt * 16 + dd;
        float v = 0.0f;
        if (cin < CIN && d < COUT) v = cw[((size_t)t * CIN + cin) * COUT + d];
        F2t[i] = bf16e(v);
    } else if (i < total1 + total2) {
        int j = i - total1;
        int d = j / CINP, c = j % CINP;
        float v = 0.0f;
        if (c < CIN && d < COUT) v = dw[(size_t)c * COUT + d];
        FD[j] = bf16e(v);
    }
    if (i < COUT) B[i] = cb[i] + (HAS_SELF ? db[i] : 0.0f);
}

// ---------------------------------------------------------------------------
// fused CConv, all-MFMA, W64-persistent, TM=8 / 1024 thr (16 waves, ~76KB LDS
// -> 2 blocks/CU = 32 waves/CU = 100% occupancy target):
//   geometry held in REGISTERS (thread owns one (pt,k) entry)
//   step1: 2 waves per point (2 mt-tiles each); step2: 16 waves, SPLITK=16/NT
//   per cc: step1 -> bar -> [stage(cc+1) || step2] -> bar
// NOTE: MFMA is wave-cooperative — never branch around it with a
//       lane-divergent condition; zero the fragments instead (round-8 bug).
// NOTE: TM<8 doubles step2 M-waste (round-12 regression) — keep TM=8.
// OUT_MODE: 0 = X-slice, 1 = plain, 2 = +resid, 3 = final pos/vel
// ---------------------------------------------------------------------------
template <int CIN, int COUT, int HAS_SELF, int RELU_IN, int OUT_MODE>
__global__ void __launch_bounds__(1024, 8) pn_cconv(
    const float* __restrict__ qpos, const float* __restrict__ ppos,
    const float* __restrict__ feats, const int* __restrict__ nbr,
    const unsigned short* __restrict__ F2t, const unsigned short* __restrict__ FD,
    const float* __restrict__ bias,
    const float* __restrict__ resid, float* __restrict__ outp,
    const float* __restrict__ pos0, int out_stride, int out_off)
{
    constexpr int CINP   = ((CIN + 15) / 16) * 16;
    constexpr int NCC    = CINP / 16;
    constexpr int DPAD   = ((COUT + 15) / 16) * 16;
    constexpr int NT     = DPAD / 16;
    constexpr int NWAVE  = 16;            // waves per block
    constexpr int SPLITK = NWAVE / NT;
    constexpr int SPC2   = 32 / SPLITK;   // 32-wide K-steps per wave in step2
    constexpr int WST    = 48;            // row stride (bf16), 96B, 16B-aligned
    constexpr int A2ST   = 1032;          // A2 row stride (2064B, 16B-aligned)

    __shared__ __align__(16) unsigned short sW [TM * 64 * WST];   // 49152B
    __shared__ __align__(16) unsigned short sFT[TM * 16 * WST];   // 12288B
    __shared__ __align__(16) unsigned short sA2[TM * A2ST];       // 16512B

    float*          sEpi = (float*)sW;             // 16KB, after sW dead (post cc-loop)
    unsigned short* sA3  = sFT + 4096;             // bytes 8192.., after sFT dead

    const int tid  = threadIdx.x;
    const int w    = tid >> 6;
    const int lane = tid & 63;
    const int n16  = lane & 15;
    const int kg   = lane >> 4;
    const int pt0  = blockIdx.x * TM;
    const int dt   = w % NT;
    const int kh   = w / NT;

    // phase 0: geometry into REGISTERS (thread owns entry (myPt, myK))
    const int myPt = tid / KN;
    const int myK  = tid - myPt * KN;
    int      myId  = -1;
    unsigned g[8];
    if (tid < TM * KN) {
        int q = pt0 + myPt;
        myId  = nbr[q * KN + myK];
        if (myId >= 0) {
            float rx = (ppos[myId * 3 + 0] - qpos[q * 3 + 0]) * (1.0f / 0.1125f);
            float ry = (ppos[myId * 3 + 1] - qpos[q * 3 + 1]) * (1.0f / 0.1125f);
            float rz = (ppos[myId * 3 + 2] - qpos[q * 3 + 2]) * (1.0f / 0.1125f);
            pn_geom(rx, ry, rz, g);
        }
    }

    // staging helper: thread writes its entry's 16-chan slice (zeros if invalid)
    auto stage = [&](int cc) {
        if (tid < TM * KN) {
            const int cb0 = cc * 16;
            unsigned short vals[16];
            if (myId >= 0) {
                if constexpr (CIN % 16 == 0) {
                    const float4* s4 = (const float4*)(feats + (size_t)myId * CIN + cb0);
#pragma unroll
                    for (int v4 = 0; v4 < 4; ++v4) {
                        float4 f = s4[v4];
                        if (RELU_IN) { f.x=fmaxf(f.x,0.f); f.y=fmaxf(f.y,0.f); f.z=fmaxf(f.z,0.f); f.w=fmaxf(f.w,0.f); }
                        vals[v4*4+0] = bf16e(f.x); vals[v4*4+1] = bf16e(f.y);
                        vals[v4*4+2] = bf16e(f.z); vals[v4*4+3] = bf16e(f.w);
                    }
                } else {
#pragma unroll
                    for (int c = 0; c < 16; ++c) {
                        float f = (cb0 + c < CIN) ? feats[(size_t)myId * CIN + cb0 + c] : 0.0f;
                        if (RELU_IN) f = fmaxf(f, 0.0f);
                        vals[c] = bf16e(f);
                    }
                }
            } else {
#pragma unroll
                for (int c = 0; c < 16; ++c) vals[c] = 0;
            }
#pragma unroll
            for (int c = 0; c < 16; ++c) sFT[(myPt * 16 + c) * WST + myK] = vals[c];
        }
    };

    // zero W64 once
    {
        uint4 z4 = make_uint4(0, 0, 0, 0);
        for (int i = tid; i < TM * 64 * WST / 8; i += 1024) ((uint4*)sW)[i] = z4;
    }
    __syncthreads();
    // scatter W64 from register geometry (write-once, no atomics) + stage cc=0
    if (tid < TM * KN && myId >= 0) {
#pragma unroll
        for (int j = 0; j < 8; ++j)
            sW[(myPt * 64 + (int)(g[j] >> 16)) * WST + myK] = (unsigned short)(g[j] & 0xffffu);
    }
    stage(0);

    f32x4 accA = {0.0f, 0.0f, 0.0f, 0.0f};
    f32x4 accB = {0.0f, 0.0f, 0.0f, 0.0f};
    const short8 z8 = {0,0,0,0,0,0,0,0};
    __syncthreads();

    for (int cc = 0; cc < NCC; ++cc) {
        // step1: 2 waves per point, 2 mt-tiles each; wave w -> pt w>>1, mts (w&1)*2..+1
        {
            const int spt = w >> 1;
            const int mt0 = (w & 1) * 2;
            short8 bvv[2];
#pragma unroll
            for (int s = 0; s < 2; ++s) {
                int kidx = s * 32 + kg * 8;
                bvv[s] = z8;
                if (kidx < KN)
                    bvv[s] = *(const short8*)(sFT + (spt * 16 + n16) * WST + kidx);
            }
#pragma unroll
            for (int m = 0; m < 2; ++m) {
                const int mt = mt0 + m;
                f32x4 a1 = {0.0f, 0.0f, 0.0f, 0.0f};
#pragma unroll
                for (int s = 0; s < 2; ++s) {
                    int kidx = s * 32 + kg * 8;
                    short8 av = z8;
                    if (kidx < KN)
                        av = *(const short8*)(sW + (spt * 64 + mt * 16 + n16) * WST + kidx);
                    a1 = __builtin_amdgcn_mfma_f32_16x16x32_bf16(av, bvv[s], a1, 0, 0, 0);
                }
#pragma unroll
                for (int r = 0; r < 4; ++r)
                    sA2[spt * A2ST + (mt * 16 + kg * 4 + r) * 16 + n16] = bf16e(a1[r]);
            }
        }
        __syncthreads();

        // stage(cc+1) overlapped with step2 (independent LDS regions)
        if (cc + 1 < NCC) stage(cc + 1);

        // step2: acc += A2(TM pts x 1024) * F2t(1024 x DPAD); wave (dt,kh); dual acc
        {
            const unsigned short* gB = F2t + ((size_t)((cc * NT + dt) * 16 + n16)) * 1024;
            const int s0 = kh * SPC2;
#pragma unroll 4
            for (int s2 = 0; s2 < SPC2; ++s2) {
                int k2 = (s0 + s2) * 32 + kg * 8;
                short8 av = (n16 < TM) ? *(const short8*)(sA2 + n16 * A2ST + k2) : z8;
                short8 bv = *(const short8*)(gB + k2);
                if (s2 & 1) accB = __builtin_amdgcn_mfma_f32_16x16x32_bf16(av, bv, accB, 0, 0, 0);
                else        accA = __builtin_amdgcn_mfma_f32_16x16x32_bf16(av, bv, accA, 0, 0, 0);
            }
        }
        __syncthreads();
    }

    // self/dense branch: acc += relu(self feats) x FD   (sA3 aliases dead sFT)
    if constexpr (HAS_SELF) {
        constexpr int NP = NCC / 2;
        for (int ccp = 0; ccp < NP; ++ccp) {
            if (tid < TM * 32) {
                int pt = tid / 32, c = tid & 31;
                int cin = ccp * 32 + c;
                float f = (cin < CIN) ? feats[(size_t)(pt0 + pt) * CIN + cin] : 0.0f;
                if (RELU_IN) f = fmaxf(f, 0.0f);
                sA3[pt * 40 + c] = bf16e(f);
            }
            __syncthreads();
            if (ccp % SPLITK == kh) {    // wave-uniform condition: safe around MFMA
                short8 av = (n16 < TM) ? *(const short8*)(sA3 + n16 * 40 + kg * 8) : z8;
                short8 bv = *(const short8*)(FD + (size_t)(dt * 16 + n16) * CINP + ccp * 32 + kg * 8);
                accA = __builtin_amdgcn_mfma_f32_16x16x32_bf16(av, bv, accA, 0, 0, 0);
            }
            __syncthreads();
        }
    }

    // epilogue: split-K combine + bias + output modes (sEpi aliases dead sW)
#pragma unroll
    for (int r = 0; r < 4; ++r) sEpi[(w * 64 + lane) * 4 + r] = accA[r] + accB[r];
    __syncthreads();

    if (w < NT) {
        float sum[4];
#pragma unroll
        for (int r = 0; r < 4; ++r) {
            float s = 0.0f;
#pragma unroll
            for (int k = 0; k < SPLITK; ++k)
                s += sEpi[((k * NT + w) * 64 + lane) * 4 + r];
            sum[r] = s;
        }
        int d = w * 16 + n16;
        if (d < COUT) {
            float b = bias[d];
#pragma unroll
            for (int r = 0; r < 4; ++r) {
                int pt = kg * 4 + r;
                if (pt < TM) {
                    int q = pt0 + pt;
                    float y = sum[r] + b;
                    if constexpr (OUT_MODE == 0) {
                        outp[q * out_stride + out_off + d] = y;
                    } else if constexpr (OUT_MODE == 1) {
                        outp[q * COUT + d] = y;
                    } else if constexpr (OUT_MODE == 2) {
                        outp[q * COUT + d] = y + resid[q * COUT + d];
                    } else {
                        float corr = y * (1.0f / 128.0f);
                        float pn   = qpos[q * 3 + d];
                        float pc   = pn + corr;
                        outp[q * 3 + d]          = pc;
                        outp[NF * 3 + q * 3 + d] = (pc - pos0[q * 3 + d]) * (1.0f / 0.02f);
                    }
                }
            }
        }
    }
}

// ---------------------------------------------------------------------------
// host launcher
// ---------------------------------------------------------------------------
extern "C" void kernel_launch(void* const* d_in, const int* in_sizes, int n_in,
                              void* d_out, int out_size, void* d_ws, size_t ws_size,
                              hipStream_t stream)
{
    (void)in_sizes; (void)n_in; (void)out_size; (void)ws_size;

    const float* pos       = (const float*)d_in[0];
    const float* vel       = (const float*)d_in[1];
    const float* box       = (const float*)d_in[2];
    const float* box_feats = (const float*)d_in[3];
    const int*   nbrf      = (const int*)d_in[4];
    const int*   nbrb      = (const int*)d_in[5];
    const float* cf0_w = (const float*)d_in[6];
    const float* cf0_b = (const float*)d_in[7];
    const float* co0_w = (const float*)d_in[8];
    const float* co0_b = (const float*)d_in[9];
    const float* d0_w  = (const float*)d_in[10];
    const float* d0_b  = (const float*)d_in[11];
    const float* c1_w  = (const float*)d_in[12];
    const float* c1_b  = (const float*)d_in[13];
    const float* d1_w  = (const float*)d_in[14];
    const float* d1_b  = (const float*)d_in[15];
    const float* c2_w  = (const float*)d_in[16];
    const float* c2_b  = (const float*)d_in[17];
    const float* d2_w  = (const float*)d_in[18];
    const float* d2_b  = (const float*)d_in[19];
    const float* c3_w  = (const float*)d_in[20];
    const float* c3_b  = (const float*)d_in[21];
    const float* d3_w  = (const float*)d_in[22];
    const float* d3_b  = (const float*)d_in[23];

    char* ws = (char*)d_ws;
    float*          POSNEW = (float*)(ws + 0);        // 98304
    float*          FEATS0 = (float*)(ws + 98304);    // 131072
    float*          X      = (float*)(ws + 229376);   // 8192*96*4 = 3145728
    float*          X1     = (float*)(ws + 3375104);  // 2097152
    float*          X2     = (float*)(ws + 5472256);  // 2097152
    unsigned short* F2T1   = (unsigned short*)(ws + 7569408); // 786432
    unsigned short* F2T2   = (unsigned short*)(ws + 8355840); // 524288
    unsigned short* F2T3   = (unsigned short*)(ws + 8880128); // 131072
    unsigned short* F2Tf   = (unsigned short*)(ws + 9011200); // 65536
    unsigned short* F2To   = (unsigned short*)(ws + 9076736); // 65536
    unsigned short* FD1    = (unsigned short*)(ws + 9142272); // 12288
    unsigned short* FD2    = (unsigned short*)(ws + 9154560); // 8192
    unsigned short* FD3    = (unsigned short*)(ws + 9162752); // 2048
    float*          B1     = (float*)(ws + 9164800);
    float*          B2     = (float*)(ws + 9165056);
    float*          B3     = (float*)(ws + 9165312);
    float*          Bf0    = (float*)(ws + 9165568);
    float*          Bo0    = (float*)(ws + 9165824);

    float* out_f = (float*)d_out;

    // packs: <CIN, COUT, HAS_SELF>; grid covers F2t + FD
    pn_pack<96, 64, 1><<<(6*4*16*1024 + 64*96 + 255) / 256, 256, 0, stream>>>(c1_w, d1_w, c1_b, d1_b, F2T1, FD1, B1);
    pn_pack<64, 64, 1><<<(4*4*16*1024 + 64*64 + 255) / 256, 256, 0, stream>>>(c2_w, d2_w, c2_b, d2_b, F2T2, FD2, B2);
    pn_pack<64, 3, 1><<<(4*1*16*1024 + 16*64 + 255) / 256, 256, 0, stream>>>(c3_w, d3_w, c3_b, d3_b, F2T3, FD3, B3);
    pn_pack<4, 32, 0><<<(1*2*16*1024 + 255) / 256, 256, 0, stream>>>(cf0_w, nullptr, cf0_b, nullptr, F2Tf, nullptr, Bf0);
    pn_pack<3, 32, 0><<<(1*2*16*1024 + 255) / 256, 256, 0, stream>>>(co0_w, nullptr, co0_b, nullptr, F2To, nullptr, Bo0);

    pn_prep<<<(NF + 255) / 256, 256, 0, stream>>>(pos, vel, nbrf, d0_w, d0_b,
                                                  POSNEW, FEATS0, X, out_f + NF * 6);

    // convs: <CIN, COUT, HAS_SELF, RELU_IN, OUT_MODE>, grid NF/8, 1024 thr
    pn_cconv<4, 32, 0, 0, 0><<<NF / TM, 1024, 0, stream>>>(
        POSNEW, POSNEW, FEATS0, nbrf, F2Tf, nullptr, Bf0, nullptr, X, nullptr, 96, 32);
    pn_cconv<3, 32, 0, 0, 0><<<NF / TM, 1024, 0, stream>>>(
        POSNEW, box, box_feats, nbrb, F2To, nullptr, Bo0, nullptr, X, nullptr, 96, 0);
    pn_cconv<96, 64, 1, 1, 1><<<NF / TM, 1024, 0, stream>>>(
        POSNEW, POSNEW, X, nbrf, F2T1, FD1, B1, nullptr, X1, nullptr, 0, 0);
    pn_cconv<64, 64, 1, 1, 2><<<NF / TM, 1024, 0, stream>>>(
        POSNEW, POSNEW, X1, nbrf, F2T2, FD2, B2, X1, X2, nullptr, 0, 0);
    pn_cconv<64, 3, 1, 1, 3><<<NF / TM, 1024, 0, stream>>>(
        POSNEW, POSNEW, X2, nbrf, F2T3, FD3, B3, nullptr, out_f, pos, 0, 0);
}

// Round 14
// 308.756 us; speedup vs baseline: 1.6947x; 1.2034x over previous
//
#include <hip/hip_runtime.h>

#define NF 8192
#define KN 48
#define TM 16

typedef __attribute__((ext_vector_type(8))) short short8;
typedef __attribute__((ext_vector_type(4))) float f32x4;

__device__ __forceinline__ unsigned short bf16e(float f) {
    return (unsigned short)((__float_as_uint(f) + 0x8000u) >> 16);
}

// ---------------------------------------------------------------------------
// geometry: ball->cube + trilinear corner weights for one neighbor
// packs 8 entries of (tap<<16 | bf16(weight)) into g[0..7]
// ---------------------------------------------------------------------------
__device__ __forceinline__ void pn_geom(float rx, float ry, float rz, unsigned* g)
{
    float d2  = rx * rx + ry * ry + rz * rz;
    float om  = 1.0f - d2;
    float win = om * om * om;
    win = fminf(fmaxf(win, 0.0f), 1.0f);

    float rxy2 = rx * rx + ry * ry;
    float rho  = sqrtf(rxy2 + rz * rz + 1e-8f);
    float rxyv = sqrtf(rxy2 + 1e-8f);
    bool  pole = (rxy2 <= 1.25f * rz * rz);
    float s    = pole ? sqrtf(3.0f * rho / (rho + fabsf(rz))) : (rho / rxyv);
    float cx = rx * s, cy = ry * s;
    float sgnz = (rz > 0.0f) ? 1.0f : ((rz < 0.0f) ? -1.0f : 0.0f);
    float cz   = pole ? sgnz * rho : 1.5f * rz;

    float rr   = sqrtf(cx * cx + cy * cy + 1e-8f);
    bool  cond = fabsf(cx) >= fabsf(cy);
    float sx = (cx >= 0.0f) ? 1.0f : -1.0f;
    float sy = (cy >= 0.0f) ? 1.0f : -1.0f;
    float safecx = (fabsf(cx) > 1e-8f) ? cx : 1.0f;
    float safecy = (fabsf(cy) > 1e-8f) ? cy : 1.0f;
    const float C4PI = 1.2732395447351628f;
    float u = cond ? (sx * rr) : (sy * C4PI * rr * atanf(cx / safecy));
    float v = cond ? (sx * C4PI * rr * atanf(cy / safecx)) : (sy * rr);
    if (rho < 1e-6f) { u = 0.0f; v = 0.0f; cz = 0.0f; }

    float tx = fminf(fmaxf((u  * 0.5f + 0.5f) * 3.0f, 0.0f), 3.0f);
    float ty = fminf(fmaxf((v  * 0.5f + 0.5f) * 3.0f, 0.0f), 3.0f);
    float tz = fminf(fmaxf((cz * 0.5f + 0.5f) * 3.0f, 0.0f), 3.0f);
    int ix = (int)floorf(tx); ix = ix < 0 ? 0 : (ix > 2 ? 2 : ix);
    int iy = (int)floorf(ty); iy = iy < 0 ? 0 : (iy > 2 ? 2 : iy);
    int iz = (int)floorf(tz); iz = iz < 0 ? 0 : (iz > 2 ? 2 : iz);
    float fx = tx - (float)ix, fy = ty - (float)iy, fz = tz - (float)iz;
    float wx0 = 1.0f - fx, wy0 = 1.0f - fy, wz0 = 1.0f - fz;

#pragma unroll
    for (int dx = 0; dx < 2; ++dx)
#pragma unroll
        for (int dy = 0; dy < 2; ++dy)
#pragma unroll
            for (int dz = 0; dz < 2; ++dz) {
                float w = (dx ? fx : wx0) * (dy ? fy : wy0) * (dz ? fz : wz0) * win;
                int tap = ((ix + dx) << 4) + ((iy + dy) << 2) + (iz + dz);
                g[(dx << 2) | (dy << 1) | dz] = ((unsigned)tap << 16) | (unsigned)bf16e(w);
            }
}

// ---------------------------------------------------------------------------
// prep: vel_new/pos_new, fluid feats, neighbor count, dense d0 branch
// ---------------------------------------------------------------------------
__global__ void __launch_bounds__(256) pn_prep(
    const float* __restrict__ pos, const float* __restrict__ vel,
    const int* __restrict__ nbrf,
    const float* __restrict__ d0w, const float* __restrict__ d0b,
    float* __restrict__ pos_new, float* __restrict__ feats0,
    float* __restrict__ X, float* __restrict__ nfn)
{
    int t = blockIdx.x * 256 + threadIdx.x;
    if (t >= NF) return;
    float vx = vel[t * 3 + 0], vy = vel[t * 3 + 1], vz = vel[t * 3 + 2];
    float vnx = vx, vny = vy - 9.81f * 0.02f, vnz = vz;
    float pnx = pos[t * 3 + 0] + (vx + vnx) * 0.01f;
    float pny = pos[t * 3 + 1] + (vy + vny) * 0.01f;
    float pnz = pos[t * 3 + 2] + (vz + vnz) * 0.01f;
    pos_new[t * 3 + 0] = pnx; pos_new[t * 3 + 1] = pny; pos_new[t * 3 + 2] = pnz;
    feats0[t * 4 + 0] = 1.0f; feats0[t * 4 + 1] = vnx;
    feats0[t * 4 + 2] = vny;  feats0[t * 4 + 3] = vnz;
    int cnt = 0;
    for (int k = 0; k < KN; ++k) cnt += (nbrf[t * KN + k] >= 0) ? 1 : 0;
    nfn[t] = (float)cnt;
    for (int j = 0; j < 32; ++j) {
        float s = d0b[j] + d0w[0 * 32 + j] + vnx * d0w[1 * 32 + j]
                + vny * d0w[2 * 32 + j] + vnz * d0w[3 * 32 + j];
        X[t * 96 + 64 + j] = s;
    }
}

// ---------------------------------------------------------------------------
// pack:  F2t[cc][dt][dd 16][k2 = tap*16+cl : 1024]  (B^T, K contiguous, bf16)
//        FD[d][CINP] (dense branch, B^T), B = cb (+db)
// ---------------------------------------------------------------------------
template <int CIN, int COUT, int HAS_SELF>
__global__ void __launch_bounds__(256) pn_pack(
    const float* __restrict__ cw, const float* __restrict__ dw,
    const float* __restrict__ cb, const float* __restrict__ db,
    unsigned short* __restrict__ F2t, unsigned short* __restrict__ FD,
    float* __restrict__ B)
{
    constexpr int CINP = ((CIN + 15) / 16) * 16;
    constexpr int NCC  = CINP / 16;
    constexpr int DPAD = ((COUT + 15) / 16) * 16;
    constexpr int NT   = DPAD / 16;
    const int total1 = NCC * NT * 16 * 1024;
    const int total2 = HAS_SELF ? DPAD * CINP : 0;
    int i = blockIdx.x * 256 + threadIdx.x;
    if (i < total1) {
        int k2 = i & 1023;
        int q  = i >> 10;
        int dd = q & 15; q >>= 4;
        int dt = q % NT;
        int cc = q / NT;
        int t   = k2 >> 4;
        int cin = cc * 16 + (k2 & 15);
        int d   = dt * 16 + dd;
        float v = 0.0f;
        if (cin < CIN && d < COUT) v = cw[((size_t)t * CIN + cin) * COUT + d];
        F2t[i] = bf16e(v);
    } else if (i < total1 + total2) {
        int j = i - total1;
        int d = j / CINP, c = j % CINP;
        float v = 0.0f;
        if (c < CIN && d < COUT) v = dw[(size_t)c * COUT + d];
        FD[j] = bf16e(v);
    }
    if (i < COUT) B[i] = cb[i] + (HAS_SELF ? db[i] : 0.0f);
}

// ---------------------------------------------------------------------------
// fused CConv, all-MFMA, W64-persistent, TM=16 / 1024 thr (16 waves, ~152KB
// LDS -> 1 block/CU). TM=16 halves the per-conv block count, and thus the
// dominant L2 F2t re-read traffic (r13 analysis: c1 is L2-BW-bound at
// ~8 TB/s; traffic = blocks x |F2t|), and makes step2 M-rows fully real.
//   geometry held in REGISTERS (thread owns one (pt,k) entry)
//   per cc: step1 (wave w -> pt w, 4 mt) -> bar -> [stage(cc+1) || step2] -> bar
// NOTE: MFMA is wave-cooperative — never branch around it with a
//       lane-divergent condition; zero the fragments instead (round-8 bug).
// OUT_MODE: 0 = X-slice, 1 = plain, 2 = +resid, 3 = final pos/vel
// ---------------------------------------------------------------------------
template <int CIN, int COUT, int HAS_SELF, int RELU_IN, int OUT_MODE>
__global__ void __launch_bounds__(1024, 4) pn_cconv(
    const float* __restrict__ qpos, const float* __restrict__ ppos,
    const float* __restrict__ feats, const int* __restrict__ nbr,
    const unsigned short* __restrict__ F2t, const unsigned short* __restrict__ FD,
    const float* __restrict__ bias,
    const float* __restrict__ resid, float* __restrict__ outp,
    const float* __restrict__ pos0, int out_stride, int out_off)
{
    constexpr int CINP   = ((CIN + 15) / 16) * 16;
    constexpr int NCC    = CINP / 16;
    constexpr int DPAD   = ((COUT + 15) / 16) * 16;
    constexpr int NT     = DPAD / 16;
    constexpr int NWAVE  = 16;            // waves per block
    constexpr int SPLITK = NWAVE / NT;
    constexpr int SPC2   = 32 / SPLITK;   // 32-wide K-steps per wave in step2
    constexpr int WST    = 48;            // row stride (bf16), 96B, 16B-aligned
    constexpr int A2ST   = 1032;          // A2 row stride (2064B, 16B-aligned)

    __shared__ __align__(16) unsigned short sW [TM * 64 * WST];   // 98304B
    __shared__ __align__(16) unsigned short sFT[TM * 16 * WST];   // 24576B
    __shared__ __align__(16) unsigned short sA2[TM * A2ST];       // 33024B

    float*          sEpi = (float*)sW;             // 16KB, after sW dead (post cc-loop)
    unsigned short* sA3  = sFT + 4096;             // bytes 8192.., after sFT dead

    const int tid  = threadIdx.x;
    const int w    = tid >> 6;
    const int lane = tid & 63;
    const int n16  = lane & 15;
    const int kg   = lane >> 4;
    const int pt0  = blockIdx.x * TM;
    const int dt   = w % NT;
    const int kh   = w / NT;

    // phase 0: geometry into REGISTERS (thread owns entry (myPt, myK))
    const int myPt = tid / KN;
    const int myK  = tid - myPt * KN;
    int      myId  = -1;
    unsigned g[8];
    if (tid < TM * KN) {
        int q = pt0 + myPt;
        myId  = nbr[q * KN + myK];
        if (myId >= 0) {
            float rx = (ppos[myId * 3 + 0] - qpos[q * 3 + 0]) * (1.0f / 0.1125f);
            float ry = (ppos[myId * 3 + 1] - qpos[q * 3 + 1]) * (1.0f / 0.1125f);
            float rz = (ppos[myId * 3 + 2] - qpos[q * 3 + 2]) * (1.0f / 0.1125f);
            pn_geom(rx, ry, rz, g);
        }
    }

    // staging helper: thread writes its entry's 16-chan slice (zeros if invalid)
    auto stage = [&](int cc) {
        if (tid < TM * KN) {
            const int cb0 = cc * 16;
            unsigned short vals[16];
            if (myId >= 0) {
                if constexpr (CIN % 16 == 0) {
                    const float4* s4 = (const float4*)(feats + (size_t)myId * CIN + cb0);
#pragma unroll
                    for (int v4 = 0; v4 < 4; ++v4) {
                        float4 f = s4[v4];
                        if (RELU_IN) { f.x=fmaxf(f.x,0.f); f.y=fmaxf(f.y,0.f); f.z=fmaxf(f.z,0.f); f.w=fmaxf(f.w,0.f); }
                        vals[v4*4+0] = bf16e(f.x); vals[v4*4+1] = bf16e(f.y);
                        vals[v4*4+2] = bf16e(f.z); vals[v4*4+3] = bf16e(f.w);
                    }
                } else {
#pragma unroll
                    for (int c = 0; c < 16; ++c) {
                        float f = (cb0 + c < CIN) ? feats[(size_t)myId * CIN + cb0 + c] : 0.0f;
                        if (RELU_IN) f = fmaxf(f, 0.0f);
                        vals[c] = bf16e(f);
                    }
                }
            } else {
#pragma unroll
                for (int c = 0; c < 16; ++c) vals[c] = 0;
            }
#pragma unroll
            for (int c = 0; c < 16; ++c) sFT[(myPt * 16 + c) * WST + myK] = vals[c];
        }
    };

    // zero W64 once
    {
        uint4 z4 = make_uint4(0, 0, 0, 0);
        for (int i = tid; i < TM * 64 * WST / 8; i += 1024) ((uint4*)sW)[i] = z4;
    }
    __syncthreads();
    // scatter W64 from register geometry (write-once, no atomics) + stage cc=0
    if (tid < TM * KN && myId >= 0) {
#pragma unroll
        for (int j = 0; j < 8; ++j)
            sW[(myPt * 64 + (int)(g[j] >> 16)) * WST + myK] = (unsigned short)(g[j] & 0xffffu);
    }
    stage(0);

    f32x4 accA = {0.0f, 0.0f, 0.0f, 0.0f};
    f32x4 accB = {0.0f, 0.0f, 0.0f, 0.0f};
    const short8 z8 = {0,0,0,0,0,0,0,0};
    __syncthreads();

    for (int cc = 0; cc < NCC; ++cc) {
        // step1 merged over mt: A2[pt][tap*16+c] for all 64 taps; wave w -> pt w
        {
            short8 bvv[2];
#pragma unroll
            for (int s = 0; s < 2; ++s) {
                int kidx = s * 32 + kg * 8;
                bvv[s] = z8;
                if (kidx < KN)
                    bvv[s] = *(const short8*)(sFT + (w * 16 + n16) * WST + kidx);
            }
#pragma unroll
            for (int mt = 0; mt < 4; ++mt) {
                f32x4 a1 = {0.0f, 0.0f, 0.0f, 0.0f};
#pragma unroll
                for (int s = 0; s < 2; ++s) {
                    int kidx = s * 32 + kg * 8;
                    short8 av = z8;
                    if (kidx < KN)
                        av = *(const short8*)(sW + (w * 64 + mt * 16 + n16) * WST + kidx);
                    a1 = __builtin_amdgcn_mfma_f32_16x16x32_bf16(av, bvv[s], a1, 0, 0, 0);
                }
#pragma unroll
                for (int r = 0; r < 4; ++r)
                    sA2[w * A2ST + (mt * 16 + kg * 4 + r) * 16 + n16] = bf16e(a1[r]);
            }
        }
        __syncthreads();

        // stage(cc+1) overlapped with step2 (independent LDS regions)
        if (cc + 1 < NCC) stage(cc + 1);

        // step2: acc += A2(16 pts x 1024) * F2t(1024 x DPAD); wave (dt,kh); dual acc
        {
            const unsigned short* gB = F2t + ((size_t)((cc * NT + dt) * 16 + n16)) * 1024;
            const int s0 = kh * SPC2;
#pragma unroll 4
            for (int s2 = 0; s2 < SPC2; ++s2) {
                int k2 = (s0 + s2) * 32 + kg * 8;
                short8 av = *(const short8*)(sA2 + n16 * A2ST + k2);
                short8 bv = *(const short8*)(gB + k2);
                if (s2 & 1) accB = __builtin_amdgcn_mfma_f32_16x16x32_bf16(av, bv, accB, 0, 0, 0);
                else        accA = __builtin_amdgcn_mfma_f32_16x16x32_bf16(av, bv, accA, 0, 0, 0);
            }
        }
        __syncthreads();
    }

    // self/dense branch: acc += relu(self feats) x FD   (sA3 aliases dead sFT)
    if constexpr (HAS_SELF) {
        constexpr int NP = NCC / 2;
        for (int ccp = 0; ccp < NP; ++ccp) {
            if (tid < TM * 32) {
                int pt = tid / 32, c = tid & 31;
                int cin = ccp * 32 + c;
                float f = (cin < CIN) ? feats[(size_t)(pt0 + pt) * CIN + cin] : 0.0f;
                if (RELU_IN) f = fmaxf(f, 0.0f);
                sA3[pt * 40 + c] = bf16e(f);
            }
            __syncthreads();
            if (ccp % SPLITK == kh) {    // wave-uniform condition: safe around MFMA
                short8 av = *(const short8*)(sA3 + n16 * 40 + kg * 8);
                short8 bv = *(const short8*)(FD + (size_t)(dt * 16 + n16) * CINP + ccp * 32 + kg * 8);
                accA = __builtin_amdgcn_mfma_f32_16x16x32_bf16(av, bv, accA, 0, 0, 0);
            }
            __syncthreads();
        }
    }

    // epilogue: split-K combine + bias + output modes (sEpi aliases dead sW)
#pragma unroll
    for (int r = 0; r < 4; ++r) sEpi[(w * 64 + lane) * 4 + r] = accA[r] + accB[r];
    __syncthreads();

    if (w < NT) {
        float sum[4];
#pragma unroll
        for (int r = 0; r < 4; ++r) {
            float s = 0.0f;
#pragma unroll
            for (int k = 0; k < SPLITK; ++k)
                s += sEpi[((k * NT + w) * 64 + lane) * 4 + r];
            sum[r] = s;
        }
        int d = w * 16 + n16;
        if (d < COUT) {
            float b = bias[d];
#pragma unroll
            for (int r = 0; r < 4; ++r) {
                int pt = kg * 4 + r;
                int q  = pt0 + pt;
                float y = sum[r] + b;
                if constexpr (OUT_MODE == 0) {
                    outp[q * out_stride + out_off + d] = y;
                } else if constexpr (OUT_MODE == 1) {
                    outp[q * COUT + d] = y;
                } else if constexpr (OUT_MODE == 2) {
                    outp[q * COUT + d] = y + resid[q * COUT + d];
                } else {
                    float corr = y * (1.0f / 128.0f);
                    float pn   = qpos[q * 3 + d];
                    float pc   = pn + corr;
                    outp[q * 3 + d]          = pc;
                    outp[NF * 3 + q * 3 + d] = (pc - pos0[q * 3 + d]) * (1.0f / 0.02f);
                }
            }
        }
    }
}

// ---------------------------------------------------------------------------
// host launcher
// ---------------------------------------------------------------------------
extern "C" void kernel_launch(void* const* d_in, const int* in_sizes, int n_in,
                              void* d_out, int out_size, void* d_ws, size_t ws_size,
                              hipStream_t stream)
{
    (void)in_sizes; (void)n_in; (void)out_size; (void)ws_size;

    const float* pos       = (const float*)d_in[0];
    const float* vel       = (const float*)d_in[1];
    const float* box       = (const float*)d_in[2];
    const float* box_feats = (const float*)d_in[3];
    const int*   nbrf      = (const int*)d_in[4];
    const int*   nbrb      = (const int*)d_in[5];
    const float* cf0_w = (const float*)d_in[6];
    const float* cf0_b = (const float*)d_in[7];
    const float* co0_w = (const float*)d_in[8];
    const float* co0_b = (const float*)d_in[9];
    const float* d0_w  = (const float*)d_in[10];
    const float* d0_b  = (const float*)d_in[11];
    const float* c1_w  = (const float*)d_in[12];
    const float* c1_b  = (const float*)d_in[13];
    const float* d1_w  = (const float*)d_in[14];
    const float* d1_b  = (const float*)d_in[15];
    const float* c2_w  = (const float*)d_in[16];
    const float* c2_b  = (const float*)d_in[17];
    const float* d2_w  = (const float*)d_in[18];
    const float* d2_b  = (const float*)d_in[19];
    const float* c3_w  = (const float*)d_in[20];
    const float* c3_b  = (const float*)d_in[21];
    const float* d3_w  = (const float*)d_in[22];
    const float* d3_b  = (const float*)d_in[23];

    char* ws = (char*)d_ws;
    float*          POSNEW = (float*)(ws + 0);        // 98304
    float*          FEATS0 = (float*)(ws + 98304);    // 131072
    float*          X      = (float*)(ws + 229376);   // 8192*96*4 = 3145728
    float*          X1     = (float*)(ws + 3375104);  // 2097152
    float*          X2     = (float*)(ws + 5472256);  // 2097152
    unsigned short* F2T1   = (unsigned short*)(ws + 7569408); // 786432
    unsigned short* F2T2   = (unsigned short*)(ws + 8355840); // 524288
    unsigned short* F2T3   = (unsigned short*)(ws + 8880128); // 131072
    unsigned short* F2Tf   = (unsigned short*)(ws + 9011200); // 65536
    unsigned short* F2To   = (unsigned short*)(ws + 9076736); // 65536
    unsigned short* FD1    = (unsigned short*)(ws + 9142272); // 12288
    unsigned short* FD2    = (unsigned short*)(ws + 9154560); // 8192
    unsigned short* FD3    = (unsigned short*)(ws + 9162752); // 2048
    float*          B1     = (float*)(ws + 9164800);
    float*          B2     = (float*)(ws + 9165056);
    float*          B3     = (float*)(ws + 9165312);
    float*          Bf0    = (float*)(ws + 9165568);
    float*          Bo0    = (float*)(ws + 9165824);

    float* out_f = (float*)d_out;

    // packs: <CIN, COUT, HAS_SELF>; grid covers F2t + FD
    pn_pack<96, 64, 1><<<(6*4*16*1024 + 64*96 + 255) / 256, 256, 0, stream>>>(c1_w, d1_w, c1_b, d1_b, F2T1, FD1, B1);
    pn_pack<64, 64, 1><<<(4*4*16*1024 + 64*64 + 255) / 256, 256, 0, stream>>>(c2_w, d2_w, c2_b, d2_b, F2T2, FD2, B2);
    pn_pack<64, 3, 1><<<(4*1*16*1024 + 16*64 + 255) / 256, 256, 0, stream>>>(c3_w, d3_w, c3_b, d3_b, F2T3, FD3, B3);
    pn_pack<4, 32, 0><<<(1*2*16*1024 + 255) / 256, 256, 0, stream>>>(cf0_w, nullptr, cf0_b, nullptr, F2Tf, nullptr, Bf0);
    pn_pack<3, 32, 0><<<(1*2*16*1024 + 255) / 256, 256, 0, stream>>>(co0_w, nullptr, co0_b, nullptr, F2To, nullptr, Bo0);

    pn_prep<<<(NF + 255) / 256, 256, 0, stream>>>(pos, vel, nbrf, d0_w, d0_b,
                                                  POSNEW, FEATS0, X, out_f + NF * 6);

    // convs: <CIN, COUT, HAS_SELF, RELU_IN, OUT_MODE>, grid NF/16, 1024 thr
    pn_cconv<4, 32, 0, 0, 0><<<NF / TM, 1024, 0, stream>>>(
        POSNEW, POSNEW, FEATS0, nbrf, F2Tf, nullptr, Bf0, nullptr, X, nullptr, 96, 32);
    pn_cconv<3, 32, 0, 0, 0><<<NF / TM, 1024, 0, stream>>>(
        POSNEW, box, box_feats, nbrb, F2To, nullptr, Bo0, nullptr, X, nullptr, 96, 0);
    pn_cconv<96, 64, 1, 1, 1><<<NF / TM, 1024, 0, stream>>>(
        POSNEW, POSNEW, X, nbrf, F2T1, FD1, B1, nullptr, X1, nullptr, 0, 0);
    pn_cconv<64, 64, 1, 1, 2><<<NF / TM, 1024, 0, stream>>>(
        POSNEW, POSNEW, X1, nbrf, F2T2, FD2, B2, X1, X2, nullptr, 0, 0);
    pn_cconv<64, 3, 1, 1, 3><<<NF / TM, 1024, 0, stream>>>(
        POSNEW, POSNEW, X2, nbrf, F2T3, FD3, B3, nullptr, out_f, pos, 0, 0);
}